// Round 11
// baseline (690.465 us; speedup 1.0000x reference)
//
#include <hip/hip_runtime.h>
#include <math.h>

// DiffRankNet: HGNN forward on MI355X.
// R10: k_topk rewritten barrier-free: per-wave ordered top-15 via u64 shfl
//      butterflies (no LDS/sync in the 15-round loop), single barrier, wave-0
//      merge of 60 candidates; float4 distance pass. Was 30 barriers/block.
// out = [sigmoid(y0-y1), y0, y1]

#define NN   4096
#define CC   1024
#define HIDN 512
#define FEATN 128
#define NE   12288
#define KTOT 30
#define KMAX 15
#define CH   16
#define MAXCH (NN + NN * KTOT / CH)

typedef __attribute__((ext_vector_type(4))) int i32x4;
typedef unsigned short ushort_t;

__device__ __forceinline__ unsigned short bf16_rne(float x) {
    unsigned u = __float_as_uint(x);
    unsigned r = (u + 0x7FFFu + ((u >> 16) & 1u)) >> 16;
    return (unsigned short)r;
}
__device__ __forceinline__ float bf16_lo(unsigned u) { return __uint_as_float(u << 16); }
__device__ __forceinline__ float bf16_hi(unsigned u) { return __uint_as_float(u & 0xFFFF0000u); }
__device__ __forceinline__ unsigned packbf(float a, float b) {
    return (unsigned)bf16_rne(a) | ((unsigned)bf16_rne(b) << 16);
}

__device__ __forceinline__ void async16(void* lds, const void* g) {
    __builtin_amdgcn_global_load_lds((const __attribute__((address_space(1))) unsigned int*)g,
                                     (__attribute__((address_space(3))) unsigned int*)lds, 16, 0, 0);
}

// ---------------- row squared norms + row maxabs -> quant scale ----------------
__global__ __launch_bounds__(256) void k_rownorm2(const float* __restrict__ X,
                                                  float* __restrict__ nrm,
                                                  float* __restrict__ qs) {
    __shared__ float s[256];
    __shared__ float sm[256];
    int i = blockIdx.x, t = threadIdx.x;
    const float* row = X + (size_t)i * CC;
    float acc = 0.f, mx = 0.f;
#pragma unroll
    for (int j = 0; j < CC / 256; ++j) {
        float v = row[t + 256 * j];
        acc += v * v;
        mx = fmaxf(mx, fabsf(v));
    }
    s[t] = acc; sm[t] = mx; __syncthreads();
    for (int d = 128; d > 0; d >>= 1) {
        if (t < d) { s[t] += s[t + d]; sm[t] = fmaxf(sm[t], sm[t + d]); }
        __syncthreads();
    }
    if (t == 0) { nrm[i] = s[0]; qs[i] = fmaxf(sm[0], 1e-20f) / 127.0f; }
}

// ---------------- quantize X -> i8 hi/lo ----------------
__global__ __launch_bounds__(256) void k_quant(const float* __restrict__ X,
                                               const float* __restrict__ qs,
                                               signed char* __restrict__ H,
                                               signed char* __restrict__ L) {
    int p = blockIdx.x * 256 + threadIdx.x;    // NN*CC/4
    int i = p >> 8;
    float inv = 1.0f / qs[i];
    float4 v = *reinterpret_cast<const float4*>(&X[(size_t)p * 4]);
    float f[4] = { v.x, v.y, v.z, v.w };
    char hh[4], ll[4];
#pragma unroll
    for (int j = 0; j < 4; ++j) {
        float xs = f[j] * inv;
        float h = rintf(xs);
        float l = rintf((xs - h) * 128.0f);
        hh[j] = (char)(int)h;
        ll[j] = (char)(int)l;
    }
    *reinterpret_cast<char4*>(&H[(size_t)p * 4]) = make_char4(hh[0], hh[1], hh[2], hh[3]);
    *reinterpret_cast<char4*>(&L[(size_t)p * 4]) = make_char4(ll[0], ll[1], ll[2], ll[3]);
}

// ---------------- W1 per-column maxabs ----------------
__global__ __launch_bounds__(256) void k_w1max(const float* __restrict__ W,
                                               unsigned* __restrict__ sigb) {
    int t = threadIdx.x;
    int r0 = blockIdx.x * 64;
    float m0 = 0.f, m1 = 0.f;
    for (int r = 0; r < 64; ++r) {
        const float* row = W + (size_t)(r0 + r) * HIDN;
        m0 = fmaxf(m0, fabsf(row[t]));
        m1 = fmaxf(m1, fabsf(row[t + 256]));
    }
    atomicMax(&sigb[t],       __float_as_uint(m0));
    atomicMax(&sigb[t + 256], __float_as_uint(m1));
}

__global__ __launch_bounds__(256) void k_sig(const unsigned* __restrict__ sigb,
                                             float* __restrict__ sig) {
    int i = blockIdx.x * 256 + threadIdx.x;
    sig[i] = fmaxf(__uint_as_float(sigb[i]), 1e-20f) / 127.0f;
}

// ---------------- transpose + i8-split W1 [CC][HIDN] -> [HIDN][CC] ----------------
__global__ __launch_bounds__(256) void k_wt8(const float* __restrict__ W,
                                             const float* __restrict__ sig,
                                             signed char* __restrict__ Th,
                                             signed char* __restrict__ Tl) {
    __shared__ float s[32][33];
    int bx = blockIdx.x, by = blockIdx.y;
    int tx = threadIdx.x & 31, ty = threadIdx.x >> 5;
#pragma unroll
    for (int rr = 0; rr < 4; ++rr) {
        int k = by * 32 + ty + rr * 8;
        s[ty + rr * 8][tx] = W[(size_t)k * HIDN + bx * 32 + tx];
    }
    __syncthreads();
#pragma unroll
    for (int rr = 0; rr < 4; ++rr) {
        int n = bx * 32 + ty + rr * 8;
        int k = by * 32 + tx;
        float x = s[tx][ty + rr * 8];
        float xs = x / sig[n];
        float h = rintf(xs);
        float l = rintf((xs - h) * 128.0f);
        Th[(size_t)n * CC + k] = (char)(int)h;
        Tl[(size_t)n * CC + k] = (char)(int)l;
    }
}

// ---------------- wbar[k] = sum_f W2[k][f] ----------------
__global__ __launch_bounds__(256) void k_w2bar(const float* __restrict__ W2,
                                               float* __restrict__ wbar) {
    int k = blockIdx.x * 256 + threadIdx.x;
    const float* row = W2 + (size_t)k * FEATN;
    float s = 0.f;
#pragma unroll
    for (int f = 0; f < FEATN; f += 4) {
        float4 v = *reinterpret_cast<const float4*>(&row[f]);
        s += v.x + v.y + v.z + v.w;
    }
    wbar[k] = s;
}

// ---------------- i8-split MFMA GEMM, double-buffered 2-phase ----------------
template <bool SYM, bool OUTB>
__global__ __launch_bounds__(256) void k_mm8(const signed char* __restrict__ Ah,
                                             const signed char* __restrict__ Al,
                                             const signed char* __restrict__ Bh,
                                             const signed char* __restrict__ Bl,
                                             const float* __restrict__ rs,
                                             const float* __restrict__ cs,
                                             float* __restrict__ C,
                                             ushort_t* __restrict__ Cb, int ldc) {
    int bi, bj;
    if (SYM) {
        int b0 = (int)blockIdx.x;                  // 528
        int L = (b0 & 7) * 66 + (b0 >> 3);         // XCD-contiguous stream
        int rem = L, si = 0;
        for (; si < 8; ++si) {
            int grp = 10 + (7 - si) * 16;
            if (rem < grp) break;
            rem -= grp;
        }
        int sj, u, v;
        if (rem < 10) {
            int uu = 0, r2 = rem;
            while (r2 >= 4 - uu) { r2 -= 4 - uu; ++uu; }
            u = uu; v = uu + r2; sj = si;
        } else {
            int r2 = rem - 10;
            sj = si + 1 + (r2 >> 4);
            int w2 = r2 & 15;
            u = w2 >> 2; v = w2 & 3;
        }
        bi = si * 4 + u; bj = sj * 4 + v;
    } else {
        bi = blockIdx.y; bj = blockIdx.x;
    }
    __shared__ char smem[2][4][128][64];   // 64 KB double buffer
    int t = threadIdx.x;
    int w = t >> 6, l = t & 63;
    int wr = (w >> 1) * 64, wc = (w & 1) * 64;

    i32x4 acc1[4][4], acc2[4][4];
#pragma unroll
    for (int i = 0; i < 4; ++i)
#pragma unroll
        for (int j = 0; j < 4; ++j) { acc1[i][j] = (i32x4){0,0,0,0}; acc2[i][j] = (i32x4){0,0,0,0}; }

    const signed char* src[4] = {
        Ah + (size_t)bi * 128 * 1024,
        Al + (size_t)bi * 128 * 1024,
        Bh + (size_t)bj * 128 * 1024,
        Bl + (size_t)bj * 128 * 1024
    };
    int srow = l >> 2;
    int sslot = (l & 3) ^ ((l >> 3) & 3);  // inverse-swizzled source slot

    int col = l & 15;
    int kg = l >> 4;

    auto stage = [&](int buf, int kt) {
        int k0 = kt * 64;
#pragma unroll
        for (int q = 0; q < 4; ++q) {
#pragma unroll
            for (int s2 = 0; s2 < 2; ++s2) {
                int rbase = (w * 2 + s2) * 16;
                const signed char* g = src[q] + (size_t)(rbase + srow) * 1024 + k0 + sslot * 16;
                async16(&smem[buf][q][rbase][0], g);
            }
        }
    };

    stage(0, 0);
    __syncthreads();
    int cur = 0;
    for (int kt = 0; kt < 16; ++kt) {
        if (kt + 1 < 16) stage(cur ^ 1, kt + 1);
        i32x4 ah[4], al4[4], bh4[4], bl4[4];
#pragma unroll
        for (int mi = 0; mi < 4; ++mi) {
            int row = wr + mi * 16 + col;
            int ph = kg ^ ((row >> 1) & 3);
            ah[mi]  = *reinterpret_cast<const i32x4*>(&smem[cur][0][row][ph * 16]);
            al4[mi] = *reinterpret_cast<const i32x4*>(&smem[cur][1][row][ph * 16]);
        }
#pragma unroll
        for (int nj = 0; nj < 4; ++nj) {
            int row = wc + nj * 16 + col;
            int ph = kg ^ ((row >> 1) & 3);
            bh4[nj] = *reinterpret_cast<const i32x4*>(&smem[cur][2][row][ph * 16]);
            bl4[nj] = *reinterpret_cast<const i32x4*>(&smem[cur][3][row][ph * 16]);
        }
#pragma unroll
        for (int mi = 0; mi < 4; ++mi)
#pragma unroll
            for (int nj = 0; nj < 4; ++nj) {
                acc1[mi][nj] = __builtin_amdgcn_mfma_i32_16x16x64_i8(ah[mi], bh4[nj], acc1[mi][nj], 0, 0, 0);
                acc2[mi][nj] = __builtin_amdgcn_mfma_i32_16x16x64_i8(ah[mi], bl4[nj], acc2[mi][nj], 0, 0, 0);
                acc2[mi][nj] = __builtin_amdgcn_mfma_i32_16x16x64_i8(al4[mi], bh4[nj], acc2[mi][nj], 0, 0, 0);
            }
        __syncthreads();
        cur ^= 1;
    }

    // epilogue: lane holds rows rg0..rg0+3 at column cg -> float4 along transposed dim
#pragma unroll
    for (int mi = 0; mi < 4; ++mi) {
        int rg0 = bi * 128 + wr + mi * 16 + (l >> 4) * 4;
#pragma unroll
        for (int nj = 0; nj < 4; ++nj) {
            int cg = bj * 128 + wc + nj * 16 + col;
            float csv = cs[cg];
            float vr[4];
#pragma unroll
            for (int r = 0; r < 4; ++r)
                vr[r] = ((float)acc1[mi][nj][r] + (float)acc2[mi][nj][r] * (1.0f / 128.0f))
                        * rs[rg0 + r] * csv;
            if (OUTB) {
#pragma unroll
                for (int r = 0; r < 4; ++r)
                    Cb[(size_t)(rg0 + r) * ldc + cg] = bf16_rne(vr[r]);
            } else {
#pragma unroll
                for (int r = 0; r < 4; ++r)
                    C[(size_t)(rg0 + r) * ldc + cg] = vr[r];
                if (SYM && bi != bj)
                    *reinterpret_cast<float4*>(&C[(size_t)cg * ldc + rg0]) =
                        make_float4(vr[0], vr[1], vr[2], vr[3]);
            }
        }
    }
}

// ---------------- top-15: barrier-free per-wave butterflies + single merge ----------------
// thread t owns i in [16t, 16t+16): float4 loads. Keys u64 = (fbits<<32)|i —
// lexicographic (value, index) order matches jax top_k tie-break exactly.
__global__ __launch_bounds__(256) void k_topk(const float* __restrict__ G,
                                              const float* __restrict__ nrm,
                                              int* __restrict__ idx_out) {
    __shared__ unsigned long long cand[4 * KMAX];
    int e = blockIdx.x, t = threadIdx.x;
    int lane = t & 63, w = t >> 6;
    float ne = nrm[e];
    const float* Grow = G + (size_t)e * NN;
    unsigned long long key[16];
    unsigned long long my = ~0ull;
#pragma unroll
    for (int q = 0; q < 4; ++q) {
        float4 gv = *reinterpret_cast<const float4*>(&Grow[t * 16 + q * 4]);
        float4 nv = *reinterpret_cast<const float4*>(&nrm[t * 16 + q * 4]);
        float d0 = fmaxf(ne + nv.x - 2.0f * gv.x, 0.0f);
        float d1 = fmaxf(ne + nv.y - 2.0f * gv.y, 0.0f);
        float d2 = fmaxf(ne + nv.z - 2.0f * gv.z, 0.0f);
        float d3 = fmaxf(ne + nv.w - 2.0f * gv.w, 0.0f);
        int i0 = t * 16 + q * 4;
        key[q * 4 + 0] = ((unsigned long long)__float_as_uint(d0) << 32) | (unsigned)(i0 + 0);
        key[q * 4 + 1] = ((unsigned long long)__float_as_uint(d1) << 32) | (unsigned)(i0 + 1);
        key[q * 4 + 2] = ((unsigned long long)__float_as_uint(d2) << 32) | (unsigned)(i0 + 2);
        key[q * 4 + 3] = ((unsigned long long)__float_as_uint(d3) << 32) | (unsigned)(i0 + 3);
    }
#pragma unroll
    for (int j = 0; j < 16; ++j) my = key[j] < my ? key[j] : my;

    // per-wave ordered top-15: 15 butterfly rounds, no block barriers
    unsigned long long mine = ~0ull;   // lane r keeps round-r winner
    for (int r = 0; r < KMAX; ++r) {
        unsigned long long m = my;
#pragma unroll
        for (int d = 1; d < 64; d <<= 1) {
            unsigned long long o = __shfl_xor(m, d);
            m = o < m ? o : m;
        }
        if (lane == r) mine = m;
        if (my == m) {               // unique owner (idx distinct)
#pragma unroll
            for (int jj = 0; jj < 16; ++jj) if (key[jj] == m) key[jj] = ~0ull;
            my = ~0ull;
#pragma unroll
            for (int jj = 0; jj < 16; ++jj) my = key[jj] < my ? key[jj] : my;
        }
    }
    if (lane < KMAX) cand[w * KMAX + lane] = mine;
    __syncthreads();
    if (w == 0) {
        unsigned long long ck = (lane < 4 * KMAX) ? cand[lane] : ~0ull;
        for (int r = 0; r < KMAX; ++r) {
            unsigned long long m = ck;
#pragma unroll
            for (int d = 1; d < 64; d <<= 1) {
                unsigned long long o = __shfl_xor(m, d);
                m = o < m ? o : m;
            }
            if (lane == 0) idx_out[e * 16 + r] = (int)(unsigned)m;
            if (ck == m) ck = ~0ull;
        }
    }
}

// ---------------- degrees / CSR (parallel small kernels) ----------------
__device__ __forceinline__ void decode_pair(int p, int& e, int& b, int& j) {
    e = p / KTOT;
    int q = p - e * KTOT;
    if (q < 5)       { b = 0; j = q; }
    else if (q < 15) { b = 1; j = q - 5; }
    else             { b = 2; j = q - 15; }
}

__global__ __launch_bounds__(256) void k_count(const int* __restrict__ idx, int* __restrict__ Dv) {
    int p = blockIdx.x * 256 + threadIdx.x;
    int e, b, j; decode_pair(p, e, b, j);
    (void)b;
    atomicAdd(&Dv[idx[e * 16 + j]], 1);
}

__global__ __launch_bounds__(256) void k_dv(const int* __restrict__ Dv,
                                            const float* __restrict__ qs,
                                            float* __restrict__ dvv,
                                            float* __restrict__ rs1) {
    int i = blockIdx.x * 256 + threadIdx.x;
    int d = Dv[i];
    float dv = d > 0 ? 1.0f / sqrtf((float)d) : 0.0f;
    dvv[i] = dv;
    rs1[i] = dv * qs[i];
}

__global__ __launch_bounds__(1024) void k_scan(const int* __restrict__ Dv,
                                               int* __restrict__ offs,
                                               int* __restrict__ cur,
                                               int* __restrict__ chunkoffs,
                                               int* __restrict__ nchunks) {
    __shared__ int s[1024];
    int t = threadIdx.x;
    int v[4]; int sum = 0;
#pragma unroll
    for (int j = 0; j < 4; ++j) { v[j] = Dv[t * 4 + j]; sum += v[j]; }
    s[t] = sum; __syncthreads();
    for (int d = 1; d < 1024; d <<= 1) {
        int add = (t >= d) ? s[t - d] : 0;
        __syncthreads();
        s[t] += add;
        __syncthreads();
    }
    int run = s[t] - sum;
#pragma unroll
    for (int j = 0; j < 4; ++j) { offs[t * 4 + j] = run; cur[t * 4 + j] = run; run += v[j]; }
    if (t == 1023) offs[NN] = run;
    __syncthreads();
    int c[4]; int csum = 0;
#pragma unroll
    for (int j = 0; j < 4; ++j) { c[j] = (v[j] + CH - 1) / CH; csum += c[j]; }
    s[t] = csum; __syncthreads();
    for (int d = 1; d < 1024; d <<= 1) {
        int add = (t >= d) ? s[t - d] : 0;
        __syncthreads();
        s[t] += add;
        __syncthreads();
    }
    int crun = s[t] - csum;
#pragma unroll
    for (int j = 0; j < 4; ++j) { chunkoffs[t * 4 + j] = crun; crun += c[j]; }
    if (t == 1023) { chunkoffs[NN] = crun; *nchunks = crun; }
}

__global__ __launch_bounds__(256) void k_fill(const int* __restrict__ idx,
                                              int* __restrict__ cur,
                                              int* __restrict__ adj) {
    int p = blockIdx.x * 256 + threadIdx.x;
    int e, b, j; decode_pair(p, e, b, j);
    int i = idx[e * 16 + j];
    int eg = b * NN + e;
    int pos = atomicAdd(&cur[i], 1);
    adj[pos] = eg;
}

__global__ __launch_bounds__(256) void k_tasks(const int* __restrict__ chunkoffs,
                                               int* __restrict__ task_node) {
    int i = blockIdx.x * 256 + threadIdx.x;
    int c0 = chunkoffs[i], c1 = chunkoffs[i + 1];
    for (int c = c0; c < c1; ++c) task_node[c] = i;
}

__global__ __launch_bounds__(256) void k_ze(const int* __restrict__ idx,
                                            const float* __restrict__ dvv,
                                            float* __restrict__ ze) {
    int eg = blockIdx.x * 256 + threadIdx.x;
    int b = eg >> 12, e = eg & (NN - 1);
    int kb = (b == 0) ? 5 : (b == 1) ? 10 : 15;
    const int* row = idx + e * 16;
    float s = 0.f;
    for (int j = 0; j < kb; ++j) s += dvv[row[j]];
    ze[eg] = s / (float)kb;
}

__global__ __launch_bounds__(256) void k_ascat(const int* __restrict__ idx,
                                               const float* __restrict__ ze,
                                               float* __restrict__ a) {
    int p = blockIdx.x * 256 + threadIdx.x;
    int e, b, j; decode_pair(p, e, b, j);
    atomicAdd(&a[idx[e * 16 + j]], ze[b * NN + e]);
}

// ---------------- incremental edge gather (bf16 in, bf16 out) ----------------
__global__ __launch_bounds__(256) void k_edge3(const int* __restrict__ idx,
                                               const ushort_t* __restrict__ t1b,
                                               ushort_t* __restrict__ m) {
    int p = blockIdx.x * 256 + threadIdx.x;    // NN*64
    int e = p >> 6;
    int c8 = (p & 63) * 8;
    const int* row = idx + e * 16;
    float acc[8] = {};
    auto addrow = [&](int j) {
        uint4 raw = *reinterpret_cast<const uint4*>(&t1b[(size_t)row[j] * HIDN + c8]);
        acc[0] += bf16_lo(raw.x); acc[1] += bf16_hi(raw.x);
        acc[2] += bf16_lo(raw.y); acc[3] += bf16_hi(raw.y);
        acc[4] += bf16_lo(raw.z); acc[5] += bf16_hi(raw.z);
        acc[6] += bf16_lo(raw.w); acc[7] += bf16_hi(raw.w);
    };
    auto store = [&](size_t eg, float sc) {
        uint4 o;
        o.x = packbf(acc[0] * sc, acc[1] * sc);
        o.y = packbf(acc[2] * sc, acc[3] * sc);
        o.z = packbf(acc[4] * sc, acc[5] * sc);
        o.w = packbf(acc[6] * sc, acc[7] * sc);
        *reinterpret_cast<uint4*>(&m[eg * HIDN + c8]) = o;
    };
#pragma unroll
    for (int j = 0; j < 5; ++j) addrow(j);
    store((size_t)e, 0.2f);
#pragma unroll
    for (int j = 5; j < 10; ++j) addrow(j);
    store((size_t)(NN + e), 0.1f);
#pragma unroll
    for (int j = 10; j < 15; ++j) addrow(j);
    store((size_t)(2 * NN + e), 1.0f / 15.0f);
}

// ---------------- chunked node gather (bf16 m -> f32 partial) ----------------
__global__ __launch_bounds__(256) void k_chunk(const int* __restrict__ offs,
                                               const int* __restrict__ chunkoffs,
                                               const int* __restrict__ task_node,
                                               const int* __restrict__ nchunks,
                                               const int* __restrict__ adj,
                                               const ushort_t* __restrict__ m,
                                               float* __restrict__ partial) {
    int task = blockIdx.x * 4 + threadIdx.x / 64;
    if (task >= *nchunks) return;
    int c8 = (threadIdx.x & 63) * 8;
    int i = task_node[task];
    int ck = task - chunkoffs[i];
    int q0 = offs[i] + ck * CH;
    int n = offs[i + 1] - q0;
    n = n < CH ? n : CH;
    int e[CH];
#pragma unroll
    for (int j = 0; j < CH; ++j) e[j] = (j < n) ? adj[q0 + j] : -1;
    float acc[8] = {};
#pragma unroll
    for (int j = 0; j < CH; ++j) {
        if (e[j] >= 0) {
            uint4 raw = *reinterpret_cast<const uint4*>(&m[(size_t)e[j] * HIDN + c8]);
            acc[0] += bf16_lo(raw.x); acc[1] += bf16_hi(raw.x);
            acc[2] += bf16_lo(raw.y); acc[3] += bf16_hi(raw.y);
            acc[4] += bf16_lo(raw.z); acc[5] += bf16_hi(raw.z);
            acc[6] += bf16_lo(raw.w); acc[7] += bf16_hi(raw.w);
        }
    }
    float* o = &partial[(size_t)task * HIDN + c8];
    *reinterpret_cast<float4*>(o)     = make_float4(acc[0], acc[1], acc[2], acc[3]);
    *reinterpret_cast<float4*>(o + 4) = make_float4(acc[4], acc[5], acc[6], acc[7]);
}

// ---------------- fused combine ----------------
__global__ __launch_bounds__(256) void k_comb2(const int* __restrict__ chunkoffs,
                                               const float* __restrict__ dvv,
                                               const float* __restrict__ a,
                                               const float* __restrict__ wbar,
                                               const float* __restrict__ partial,
                                               float* __restrict__ g) {
    __shared__ float s[256];
    int p = blockIdx.x * 256 + threadIdx.x;    // NN*128
    int i = p >> 7;
    int c4 = (p & 127) * 4;
    int c0 = chunkoffs[i], c1 = chunkoffs[i + 1];
    float4 acc = make_float4(0.f, 0.f, 0.f, 0.f);
    for (int c = c0; c < c1; ++c) {
        float4 v = *reinterpret_cast<const float4*>(&partial[(size_t)c * HIDN + c4]);
        acc.x += v.x; acc.y += v.y; acc.z += v.z; acc.w += v.w;
    }
    float dv = dvv[i];
    float4 wv = *reinterpret_cast<const float4*>(&wbar[c4]);
    float val = fmaxf(acc.x * dv, 0.f) * wv.x + fmaxf(acc.y * dv, 0.f) * wv.y +
                fmaxf(acc.z * dv, 0.f) * wv.z + fmaxf(acc.w * dv, 0.f) * wv.w;
    int t = threadIdx.x;
    s[t] = val; __syncthreads();
    for (int d = 64; d > 0; d >>= 1) {
        if ((t & 127) < d) s[t] += s[t + d];
        __syncthreads();
    }
    if ((t & 127) == 0) g[i] = s[t] * dv * a[i];
}

// ---------------- final reductions ----------------
__global__ __launch_bounds__(1024) void k_yred(const float* __restrict__ g,
                                               float* __restrict__ ys, int slot) {
    __shared__ float s[1024];
    int t = threadIdx.x;
    s[t] = g[t] + g[t + 1024] + g[t + 2048] + g[t + 3072];
    __syncthreads();
    for (int d = 512; d > 0; d >>= 1) { if (t < d) s[t] += s[t + d]; __syncthreads(); }
    if (t == 0) ys[slot] = s[0];
}

__global__ void k_fin(const float* __restrict__ ys, float* __restrict__ out) {
    float y0 = ys[0] / (float)NN, y1 = ys[1] / (float)NN;
    out[0] = 1.0f / (1.0f + expf(-(y0 - y1)));
    out[1] = y0;
    out[2] = y1;
}

// ---------------- launch ----------------
extern "C" void kernel_launch(void* const* d_in, const int* in_sizes, int n_in,
                              void* d_out, int out_size, void* d_ws, size_t ws_size,
                              hipStream_t stream) {
    const float* fts[2] = { (const float*)d_in[0], (const float*)d_in[1] };
    const float* W1 = (const float*)d_in[2];
    const float* W2 = (const float*)d_in[3];
    float* out = (float*)d_out;

    char* p = (char*)d_ws;
    auto alloc = [&](size_t b) { char* r = p; p += (b + 255) & ~(size_t)255; return r; };
    float* G    = (float*)alloc((size_t)NN * NN * 4);        // 64 MB; reused as chunk-partial buffer
    float* nrm  = (float*)alloc((size_t)NN * 4);
    float* qs   = (float*)alloc((size_t)NN * 4);
    int*   idx  = (int*)  alloc((size_t)NN * 16 * 4);
    int*   Dv   = (int*)  alloc((size_t)NN * 4);
    float* dvv  = (float*)alloc((size_t)NN * 4);
    float* rs1  = (float*)alloc((size_t)NN * 4);
    int*   offs = (int*)  alloc((size_t)(NN + 1) * 4);
    int*   cur  = (int*)  alloc((size_t)NN * 4);
    int*   coffs= (int*)  alloc((size_t)(NN + 1) * 4);
    int*   nch  = (int*)  alloc(4);
    int*   tnode= (int*)  alloc((size_t)MAXCH * 4);
    int*   adj  = (int*)  alloc((size_t)NN * KTOT * 4);
    signed char* Xqh = (signed char*)alloc((size_t)NN * CC);
    signed char* Xql = (signed char*)alloc((size_t)NN * CC);
    signed char* Wqh = (signed char*)alloc((size_t)HIDN * CC);
    signed char* Wql = (signed char*)alloc((size_t)HIDN * CC);
    unsigned* sigb   = (unsigned*)alloc((size_t)HIDN * 4);
    float* w1sig = (float*)alloc((size_t)HIDN * 4);
    ushort_t* t1b = (ushort_t*)alloc((size_t)NN * HIDN * 2);
    ushort_t* m   = (ushort_t*)alloc((size_t)NE * HIDN * 2);
    float* wbar = (float*)alloc((size_t)HIDN * 4);
    float* ze   = (float*)alloc((size_t)NE * 4);
    float* a    = (float*)alloc((size_t)NN * 4);
    float* g    = (float*)alloc((size_t)NN * 4);
    float* ys   = (float*)alloc(2 * 4);

    float* partial = G;   // chunk partials alias G (free after k_topk)

    hipMemsetAsync(sigb, 0, HIDN * 4, stream);
    k_w1max<<<CC / 64, 256, 0, stream>>>(W1, sigb);
    k_sig<<<HIDN / 256, 256, 0, stream>>>(sigb, w1sig);
    k_wt8<<<dim3(HIDN / 32, CC / 32), 256, 0, stream>>>(W1, w1sig, Wqh, Wql);
    k_w2bar<<<HIDN / 256, 256, 0, stream>>>(W2, wbar);

    for (int s = 0; s < 2; ++s) {
        const float* X = fts[s];
        k_rownorm2<<<NN, 256, 0, stream>>>(X, nrm, qs);
        k_quant<<<NN * CC / 4 / 256, 256, 0, stream>>>(X, qs, Xqh, Xql);
        k_mm8<true, false><<<528, 256, 0, stream>>>(Xqh, Xql, Xqh, Xql, qs, qs, G, nullptr, NN);
        k_topk<<<NN, 256, 0, stream>>>(G, nrm, idx);
        hipMemsetAsync(Dv, 0, NN * 4, stream);
        k_count<<<NN * KTOT / 256, 256, 0, stream>>>(idx, Dv);
        k_dv<<<NN / 256, 256, 0, stream>>>(Dv, qs, dvv, rs1);
        k_scan<<<1, 1024, 0, stream>>>(Dv, offs, cur, coffs, nch);
        k_fill<<<NN * KTOT / 256, 256, 0, stream>>>(idx, cur, adj);
        k_tasks<<<NN / 256, 256, 0, stream>>>(coffs, tnode);
        k_ze<<<NE / 256, 256, 0, stream>>>(idx, dvv, ze);
        hipMemsetAsync(a, 0, NN * 4, stream);
        k_ascat<<<NN * KTOT / 256, 256, 0, stream>>>(idx, ze, a);
        // conv1: t1b = bf16(dv * (X @ W1)) via i8 split; edge means; chunked gather
        k_mm8<false, true><<<dim3(HIDN / 128, NN / 128), 256, 0, stream>>>(Xqh, Xql, Wqh, Wql, rs1, w1sig, nullptr, t1b, HIDN);
        k_edge3<<<NN * 64 / 256, 256, 0, stream>>>(idx, t1b, m);
        k_chunk<<<(MAXCH + 3) / 4, 256, 0, stream>>>(offs, coffs, tnode, nch, adj, m, partial);
        // layer-2 collapsed: g[i] = a_i * (relu(u1_i) . wbar); y = sum(g)/N
        k_comb2<<<NN * 128 / 256, 256, 0, stream>>>(coffs, dvv, a, wbar, partial, g);
        k_yred<<<1, 1024, 0, stream>>>(g, ys, s);
    }
    k_fin<<<1, 1, 0, stream>>>(ys, out);
}

// Round 12
// 593.725 us; speedup vs baseline: 1.1629x; 1.1629x over previous
//
#include <hip/hip_runtime.h>
#include <math.h>

// DiffRankNet: HGNN forward on MI355X.
// R11: k_topk REVERTED to R9 structure (R10 barrier-free version halved
//      occupancy and regressed 50->115us; serial cost was the u64 butterfly
//      chain, not barriers) + float4 distance pass. Launch fusion:
//      rownorm+quant -> k_rowprep; scan absorbs dv/tasks; ze+ascat -> zescat.
// out = [sigmoid(y0-y1), y0, y1]

#define NN   4096
#define CC   1024
#define HIDN 512
#define FEATN 128
#define NE   12288
#define KTOT 30
#define KMAX 15
#define CH   16
#define MAXCH (NN + NN * KTOT / CH)

typedef __attribute__((ext_vector_type(4))) int i32x4;
typedef unsigned short ushort_t;

__device__ __forceinline__ unsigned short bf16_rne(float x) {
    unsigned u = __float_as_uint(x);
    unsigned r = (u + 0x7FFFu + ((u >> 16) & 1u)) >> 16;
    return (unsigned short)r;
}
__device__ __forceinline__ float bf16_lo(unsigned u) { return __uint_as_float(u << 16); }
__device__ __forceinline__ float bf16_hi(unsigned u) { return __uint_as_float(u & 0xFFFF0000u); }
__device__ __forceinline__ unsigned packbf(float a, float b) {
    return (unsigned)bf16_rne(a) | ((unsigned)bf16_rne(b) << 16);
}

__device__ __forceinline__ void async16(void* lds, const void* g) {
    __builtin_amdgcn_global_load_lds((const __attribute__((address_space(1))) unsigned int*)g,
                                     (__attribute__((address_space(3))) unsigned int*)lds, 16, 0, 0);
}

// ---------------- fused: row norm + maxabs + i8 hi/lo quantize ----------------
__global__ __launch_bounds__(256) void k_rowprep(const float* __restrict__ X,
                                                 float* __restrict__ nrm,
                                                 float* __restrict__ qs,
                                                 signed char* __restrict__ H,
                                                 signed char* __restrict__ L) {
    __shared__ float s[256];
    __shared__ float sm[256];
    int i = blockIdx.x, t = threadIdx.x;
    const float* row = X + (size_t)i * CC;
    float4 v = *reinterpret_cast<const float4*>(&row[t * 4]);
    float acc = v.x * v.x + v.y * v.y + v.z * v.z + v.w * v.w;
    float mx = fmaxf(fmaxf(fabsf(v.x), fabsf(v.y)), fmaxf(fabsf(v.z), fabsf(v.w)));
    s[t] = acc; sm[t] = mx; __syncthreads();
    for (int d = 128; d > 0; d >>= 1) {
        if (t < d) { s[t] += s[t + d]; sm[t] = fmaxf(sm[t], sm[t + d]); }
        __syncthreads();
    }
    float q = fmaxf(sm[0], 1e-20f) / 127.0f;
    if (t == 0) { nrm[i] = s[0]; qs[i] = q; }
    float inv = 1.0f / q;
    float f[4] = { v.x, v.y, v.z, v.w };
    char hh[4], ll[4];
#pragma unroll
    for (int j = 0; j < 4; ++j) {
        float xs = f[j] * inv;
        float h = rintf(xs);
        float l = rintf((xs - h) * 128.0f);
        hh[j] = (char)(int)h;
        ll[j] = (char)(int)l;
    }
    *reinterpret_cast<char4*>(&H[(size_t)i * CC + t * 4]) = make_char4(hh[0], hh[1], hh[2], hh[3]);
    *reinterpret_cast<char4*>(&L[(size_t)i * CC + t * 4]) = make_char4(ll[0], ll[1], ll[2], ll[3]);
}

// ---------------- W1 per-column maxabs ----------------
__global__ __launch_bounds__(256) void k_w1max(const float* __restrict__ W,
                                               unsigned* __restrict__ sigb) {
    int t = threadIdx.x;
    int r0 = blockIdx.x * 64;
    float m0 = 0.f, m1 = 0.f;
    for (int r = 0; r < 64; ++r) {
        const float* row = W + (size_t)(r0 + r) * HIDN;
        m0 = fmaxf(m0, fabsf(row[t]));
        m1 = fmaxf(m1, fabsf(row[t + 256]));
    }
    atomicMax(&sigb[t],       __float_as_uint(m0));
    atomicMax(&sigb[t + 256], __float_as_uint(m1));
}

__global__ __launch_bounds__(256) void k_sig(const unsigned* __restrict__ sigb,
                                             float* __restrict__ sig) {
    int i = blockIdx.x * 256 + threadIdx.x;
    sig[i] = fmaxf(__uint_as_float(sigb[i]), 1e-20f) / 127.0f;
}

// ---------------- transpose + i8-split W1 [CC][HIDN] -> [HIDN][CC] ----------------
__global__ __launch_bounds__(256) void k_wt8(const float* __restrict__ W,
                                             const float* __restrict__ sig,
                                             signed char* __restrict__ Th,
                                             signed char* __restrict__ Tl) {
    __shared__ float s[32][33];
    int bx = blockIdx.x, by = blockIdx.y;
    int tx = threadIdx.x & 31, ty = threadIdx.x >> 5;
#pragma unroll
    for (int rr = 0; rr < 4; ++rr) {
        int k = by * 32 + ty + rr * 8;
        s[ty + rr * 8][tx] = W[(size_t)k * HIDN + bx * 32 + tx];
    }
    __syncthreads();
#pragma unroll
    for (int rr = 0; rr < 4; ++rr) {
        int n = bx * 32 + ty + rr * 8;
        int k = by * 32 + tx;
        float x = s[tx][ty + rr * 8];
        float xs = x / sig[n];
        float h = rintf(xs);
        float l = rintf((xs - h) * 128.0f);
        Th[(size_t)n * CC + k] = (char)(int)h;
        Tl[(size_t)n * CC + k] = (char)(int)l;
    }
}

// ---------------- wbar[k] = sum_f W2[k][f] ----------------
__global__ __launch_bounds__(256) void k_w2bar(const float* __restrict__ W2,
                                               float* __restrict__ wbar) {
    int k = blockIdx.x * 256 + threadIdx.x;
    const float* row = W2 + (size_t)k * FEATN;
    float s = 0.f;
#pragma unroll
    for (int f = 0; f < FEATN; f += 4) {
        float4 v = *reinterpret_cast<const float4*>(&row[f]);
        s += v.x + v.y + v.z + v.w;
    }
    wbar[k] = s;
}

// ---------------- i8-split MFMA GEMM, double-buffered 2-phase ----------------
template <bool SYM, bool OUTB>
__global__ __launch_bounds__(256) void k_mm8(const signed char* __restrict__ Ah,
                                             const signed char* __restrict__ Al,
                                             const signed char* __restrict__ Bh,
                                             const signed char* __restrict__ Bl,
                                             const float* __restrict__ rs,
                                             const float* __restrict__ cs,
                                             float* __restrict__ C,
                                             ushort_t* __restrict__ Cb, int ldc) {
    int bi, bj;
    if (SYM) {
        int b0 = (int)blockIdx.x;                  // 528
        int L = (b0 & 7) * 66 + (b0 >> 3);         // XCD-contiguous stream
        int rem = L, si = 0;
        for (; si < 8; ++si) {
            int grp = 10 + (7 - si) * 16;
            if (rem < grp) break;
            rem -= grp;
        }
        int sj, u, v;
        if (rem < 10) {
            int uu = 0, r2 = rem;
            while (r2 >= 4 - uu) { r2 -= 4 - uu; ++uu; }
            u = uu; v = uu + r2; sj = si;
        } else {
            int r2 = rem - 10;
            sj = si + 1 + (r2 >> 4);
            int w2 = r2 & 15;
            u = w2 >> 2; v = w2 & 3;
        }
        bi = si * 4 + u; bj = sj * 4 + v;
    } else {
        bi = blockIdx.y; bj = blockIdx.x;
    }
    __shared__ char smem[2][4][128][64];   // 64 KB double buffer
    int t = threadIdx.x;
    int w = t >> 6, l = t & 63;
    int wr = (w >> 1) * 64, wc = (w & 1) * 64;

    i32x4 acc1[4][4], acc2[4][4];
#pragma unroll
    for (int i = 0; i < 4; ++i)
#pragma unroll
        for (int j = 0; j < 4; ++j) { acc1[i][j] = (i32x4){0,0,0,0}; acc2[i][j] = (i32x4){0,0,0,0}; }

    const signed char* src[4] = {
        Ah + (size_t)bi * 128 * 1024,
        Al + (size_t)bi * 128 * 1024,
        Bh + (size_t)bj * 128 * 1024,
        Bl + (size_t)bj * 128 * 1024
    };
    int srow = l >> 2;
    int sslot = (l & 3) ^ ((l >> 3) & 3);  // inverse-swizzled source slot

    int col = l & 15;
    int kg = l >> 4;

    auto stage = [&](int buf, int kt) {
        int k0 = kt * 64;
#pragma unroll
        for (int q = 0; q < 4; ++q) {
#pragma unroll
            for (int s2 = 0; s2 < 2; ++s2) {
                int rbase = (w * 2 + s2) * 16;
                const signed char* g = src[q] + (size_t)(rbase + srow) * 1024 + k0 + sslot * 16;
                async16(&smem[buf][q][rbase][0], g);
            }
        }
    };

    stage(0, 0);
    __syncthreads();
    int cur = 0;
    for (int kt = 0; kt < 16; ++kt) {
        if (kt + 1 < 16) stage(cur ^ 1, kt + 1);
        i32x4 ah[4], al4[4], bh4[4], bl4[4];
#pragma unroll
        for (int mi = 0; mi < 4; ++mi) {
            int row = wr + mi * 16 + col;
            int ph = kg ^ ((row >> 1) & 3);
            ah[mi]  = *reinterpret_cast<const i32x4*>(&smem[cur][0][row][ph * 16]);
            al4[mi] = *reinterpret_cast<const i32x4*>(&smem[cur][1][row][ph * 16]);
        }
#pragma unroll
        for (int nj = 0; nj < 4; ++nj) {
            int row = wc + nj * 16 + col;
            int ph = kg ^ ((row >> 1) & 3);
            bh4[nj] = *reinterpret_cast<const i32x4*>(&smem[cur][2][row][ph * 16]);
            bl4[nj] = *reinterpret_cast<const i32x4*>(&smem[cur][3][row][ph * 16]);
        }
#pragma unroll
        for (int mi = 0; mi < 4; ++mi)
#pragma unroll
            for (int nj = 0; nj < 4; ++nj) {
                acc1[mi][nj] = __builtin_amdgcn_mfma_i32_16x16x64_i8(ah[mi], bh4[nj], acc1[mi][nj], 0, 0, 0);
                acc2[mi][nj] = __builtin_amdgcn_mfma_i32_16x16x64_i8(ah[mi], bl4[nj], acc2[mi][nj], 0, 0, 0);
                acc2[mi][nj] = __builtin_amdgcn_mfma_i32_16x16x64_i8(al4[mi], bh4[nj], acc2[mi][nj], 0, 0, 0);
            }
        __syncthreads();
        cur ^= 1;
    }

    // epilogue: lane holds rows rg0..rg0+3 at column cg -> float4 along transposed dim
#pragma unroll
    for (int mi = 0; mi < 4; ++mi) {
        int rg0 = bi * 128 + wr + mi * 16 + (l >> 4) * 4;
#pragma unroll
        for (int nj = 0; nj < 4; ++nj) {
            int cg = bj * 128 + wc + nj * 16 + col;
            float csv = cs[cg];
            float vr[4];
#pragma unroll
            for (int r = 0; r < 4; ++r)
                vr[r] = ((float)acc1[mi][nj][r] + (float)acc2[mi][nj][r] * (1.0f / 128.0f))
                        * rs[rg0 + r] * csv;
            if (OUTB) {
#pragma unroll
                for (int r = 0; r < 4; ++r)
                    Cb[(size_t)(rg0 + r) * ldc + cg] = bf16_rne(vr[r]);
            } else {
#pragma unroll
                for (int r = 0; r < 4; ++r)
                    C[(size_t)(rg0 + r) * ldc + cg] = vr[r];
                if (SYM && bi != bj)
                    *reinterpret_cast<float4*>(&C[(size_t)cg * ldc + rg0]) =
                        make_float4(vr[0], vr[1], vr[2], vr[3]);
            }
        }
    }
}

// ---------------- top-15 (R9 structure): register keys, block-reduce rounds ----------------
// thread t owns i in [16t, 16t+16) (float4 loads); winner owner t = win>>4.
__global__ __launch_bounds__(256) void k_topk(const float* __restrict__ G,
                                              const float* __restrict__ nrm,
                                              int* __restrict__ idx_out) {
    __shared__ unsigned long long wsm[4];
    int e = blockIdx.x, t = threadIdx.x;
    float ne = nrm[e];
    const float* Grow = G + (size_t)e * NN;
    unsigned long long key[16];
    unsigned long long my = ~0ull;
#pragma unroll
    for (int q = 0; q < 4; ++q) {
        float4 gv = *reinterpret_cast<const float4*>(&Grow[t * 16 + q * 4]);
        float4 nv = *reinterpret_cast<const float4*>(&nrm[t * 16 + q * 4]);
        float d0 = fmaxf(ne + nv.x - 2.0f * gv.x, 0.0f);
        float d1 = fmaxf(ne + nv.y - 2.0f * gv.y, 0.0f);
        float d2 = fmaxf(ne + nv.z - 2.0f * gv.z, 0.0f);
        float d3 = fmaxf(ne + nv.w - 2.0f * gv.w, 0.0f);
        int i0 = t * 16 + q * 4;
        key[q * 4 + 0] = ((unsigned long long)__float_as_uint(d0) << 32) | (unsigned)(i0 + 0);
        key[q * 4 + 1] = ((unsigned long long)__float_as_uint(d1) << 32) | (unsigned)(i0 + 1);
        key[q * 4 + 2] = ((unsigned long long)__float_as_uint(d2) << 32) | (unsigned)(i0 + 2);
        key[q * 4 + 3] = ((unsigned long long)__float_as_uint(d3) << 32) | (unsigned)(i0 + 3);
    }
#pragma unroll
    for (int j = 0; j < 16; ++j) my = key[j] < my ? key[j] : my;

    for (int r = 0; r < KMAX; ++r) {
        unsigned long long m = my;
#pragma unroll
        for (int d = 1; d < 64; d <<= 1) {
            unsigned long long o = __shfl_xor(m, d);
            m = o < m ? o : m;
        }
        if ((t & 63) == 0) wsm[t >> 6] = m;
        __syncthreads();
        unsigned long long b0 = wsm[0] < wsm[1] ? wsm[0] : wsm[1];
        unsigned long long b1 = wsm[2] < wsm[3] ? wsm[2] : wsm[3];
        unsigned long long bk = b0 < b1 ? b0 : b1;
        int win = (int)(unsigned)bk;
        if (t == 0) idx_out[e * 16 + r] = win;
        if (t == (win >> 4)) {
            int jw = win & 15;
#pragma unroll
            for (int jj = 0; jj < 16; ++jj) if (jj == jw) key[jj] = ~0ull;
            my = ~0ull;
#pragma unroll
            for (int jj = 0; jj < 16; ++jj) my = key[jj] < my ? key[jj] : my;
        }
        __syncthreads();
    }
}

// ---------------- degrees / CSR (parallel small kernels) ----------------
__device__ __forceinline__ void decode_pair(int p, int& e, int& b, int& j) {
    e = p / KTOT;
    int q = p - e * KTOT;
    if (q < 5)       { b = 0; j = q; }
    else if (q < 15) { b = 1; j = q - 5; }
    else             { b = 2; j = q - 15; }
}

__global__ __launch_bounds__(256) void k_count(const int* __restrict__ idx, int* __restrict__ Dv) {
    int p = blockIdx.x * 256 + threadIdx.x;
    int e, b, j; decode_pair(p, e, b, j);
    (void)b;
    atomicAdd(&Dv[idx[e * 16 + j]], 1);
}

// scan: degrees -> offs/cur; chunk counts -> coffs/nchunks/tnode; dvv, rs1.
__global__ __launch_bounds__(1024) void k_scan(const int* __restrict__ Dv,
                                               const float* __restrict__ qs,
                                               float* __restrict__ dvv,
                                               float* __restrict__ rs1,
                                               int* __restrict__ offs,
                                               int* __restrict__ cur,
                                               int* __restrict__ chunkoffs,
                                               int* __restrict__ nchunks,
                                               int* __restrict__ tnode) {
    __shared__ int s[1024];
    int t = threadIdx.x;
    int v[4]; int sum = 0;
#pragma unroll
    for (int j = 0; j < 4; ++j) { v[j] = Dv[t * 4 + j]; sum += v[j]; }
#pragma unroll
    for (int j = 0; j < 4; ++j) {
        int i = t * 4 + j;
        float dv = v[j] > 0 ? 1.0f / sqrtf((float)v[j]) : 0.0f;
        dvv[i] = dv;
        rs1[i] = dv * qs[i];
    }
    s[t] = sum; __syncthreads();
    for (int d = 1; d < 1024; d <<= 1) {
        int add = (t >= d) ? s[t - d] : 0;
        __syncthreads();
        s[t] += add;
        __syncthreads();
    }
    int run = s[t] - sum;
#pragma unroll
    for (int j = 0; j < 4; ++j) { offs[t * 4 + j] = run; cur[t * 4 + j] = run; run += v[j]; }
    if (t == 1023) offs[NN] = run;
    __syncthreads();
    int c[4]; int csum = 0;
#pragma unroll
    for (int j = 0; j < 4; ++j) { c[j] = (v[j] + CH - 1) / CH; csum += c[j]; }
    s[t] = csum; __syncthreads();
    for (int d = 1; d < 1024; d <<= 1) {
        int add = (t >= d) ? s[t - d] : 0;
        __syncthreads();
        s[t] += add;
        __syncthreads();
    }
    int crun = s[t] - csum;
#pragma unroll
    for (int j = 0; j < 4; ++j) {
        chunkoffs[t * 4 + j] = crun;
        for (int q = 0; q < c[j]; ++q) tnode[crun + q] = t * 4 + j;
        crun += c[j];
    }
    if (t == 1023) { chunkoffs[NN] = crun; *nchunks = crun; }
}

__global__ __launch_bounds__(256) void k_fill(const int* __restrict__ idx,
                                              int* __restrict__ cur,
                                              int* __restrict__ adj) {
    int p = blockIdx.x * 256 + threadIdx.x;
    int e, b, j; decode_pair(p, e, b, j);
    int i = idx[e * 16 + j];
    int eg = b * NN + e;
    int pos = atomicAdd(&cur[i], 1);
    adj[pos] = eg;
}

// fused: ze_e = (1/k) sum dv, then scatter ze to members (a = A 1)
__global__ __launch_bounds__(256) void k_zescat(const int* __restrict__ idx,
                                                const float* __restrict__ dvv,
                                                float* __restrict__ a) {
    int eg = blockIdx.x * 256 + threadIdx.x;   // NE threads; b uniform per block
    int b = eg >> 12, e = eg & (NN - 1);
    int kb = (b == 0) ? 5 : (b == 1) ? 10 : 15;
    const int* row = idx + e * 16;
    float s = 0.f;
    for (int j = 0; j < kb; ++j) s += dvv[row[j]];
    float ze = s / (float)kb;
    for (int j = 0; j < kb; ++j) atomicAdd(&a[row[j]], ze);
}

// ---------------- incremental edge gather (bf16 in, bf16 out) ----------------
__global__ __launch_bounds__(256) void k_edge3(const int* __restrict__ idx,
                                               const ushort_t* __restrict__ t1b,
                                               ushort_t* __restrict__ m) {
    int p = blockIdx.x * 256 + threadIdx.x;    // NN*64
    int e = p >> 6;
    int c8 = (p & 63) * 8;
    const int* row = idx + e * 16;
    float acc[8] = {};
    auto addrow = [&](int j) {
        uint4 raw = *reinterpret_cast<const uint4*>(&t1b[(size_t)row[j] * HIDN + c8]);
        acc[0] += bf16_lo(raw.x); acc[1] += bf16_hi(raw.x);
        acc[2] += bf16_lo(raw.y); acc[3] += bf16_hi(raw.y);
        acc[4] += bf16_lo(raw.z); acc[5] += bf16_hi(raw.z);
        acc[6] += bf16_lo(raw.w); acc[7] += bf16_hi(raw.w);
    };
    auto store = [&](size_t eg, float sc) {
        uint4 o;
        o.x = packbf(acc[0] * sc, acc[1] * sc);
        o.y = packbf(acc[2] * sc, acc[3] * sc);
        o.z = packbf(acc[4] * sc, acc[5] * sc);
        o.w = packbf(acc[6] * sc, acc[7] * sc);
        *reinterpret_cast<uint4*>(&m[eg * HIDN + c8]) = o;
    };
#pragma unroll
    for (int j = 0; j < 5; ++j) addrow(j);
    store((size_t)e, 0.2f);
#pragma unroll
    for (int j = 5; j < 10; ++j) addrow(j);
    store((size_t)(NN + e), 0.1f);
#pragma unroll
    for (int j = 10; j < 15; ++j) addrow(j);
    store((size_t)(2 * NN + e), 1.0f / 15.0f);
}

// ---------------- chunked node gather (bf16 m -> f32 partial) ----------------
__global__ __launch_bounds__(256) void k_chunk(const int* __restrict__ offs,
                                               const int* __restrict__ chunkoffs,
                                               const int* __restrict__ task_node,
                                               const int* __restrict__ nchunks,
                                               const int* __restrict__ adj,
                                               const ushort_t* __restrict__ m,
                                               float* __restrict__ partial) {
    int task = blockIdx.x * 4 + threadIdx.x / 64;
    if (task >= *nchunks) return;
    int c8 = (threadIdx.x & 63) * 8;
    int i = task_node[task];
    int ck = task - chunkoffs[i];
    int q0 = offs[i] + ck * CH;
    int n = offs[i + 1] - q0;
    n = n < CH ? n : CH;
    int e[CH];
#pragma unroll
    for (int j = 0; j < CH; ++j) e[j] = (j < n) ? adj[q0 + j] : -1;
    float acc[8] = {};
#pragma unroll
    for (int j = 0; j < CH; ++j) {
        if (e[j] >= 0) {
            uint4 raw = *reinterpret_cast<const uint4*>(&m[(size_t)e[j] * HIDN + c8]);
            acc[0] += bf16_lo(raw.x); acc[1] += bf16_hi(raw.x);
            acc[2] += bf16_lo(raw.y); acc[3] += bf16_hi(raw.y);
            acc[4] += bf16_lo(raw.z); acc[5] += bf16_hi(raw.z);
            acc[6] += bf16_lo(raw.w); acc[7] += bf16_hi(raw.w);
        }
    }
    float* o = &partial[(size_t)task * HIDN + c8];
    *reinterpret_cast<float4*>(o)     = make_float4(acc[0], acc[1], acc[2], acc[3]);
    *reinterpret_cast<float4*>(o + 4) = make_float4(acc[4], acc[5], acc[6], acc[7]);
}

// ---------------- fused combine ----------------
__global__ __launch_bounds__(256) void k_comb2(const int* __restrict__ chunkoffs,
                                               const float* __restrict__ dvv,
                                               const float* __restrict__ a,
                                               const float* __restrict__ wbar,
                                               const float* __restrict__ partial,
                                               float* __restrict__ g) {
    __shared__ float s[256];
    int p = blockIdx.x * 256 + threadIdx.x;    // NN*128
    int i = p >> 7;
    int c4 = (p & 127) * 4;
    int c0 = chunkoffs[i], c1 = chunkoffs[i + 1];
    float4 acc = make_float4(0.f, 0.f, 0.f, 0.f);
    for (int c = c0; c < c1; ++c) {
        float4 v = *reinterpret_cast<const float4*>(&partial[(size_t)c * HIDN + c4]);
        acc.x += v.x; acc.y += v.y; acc.z += v.z; acc.w += v.w;
    }
    float dv = dvv[i];
    float4 wv = *reinterpret_cast<const float4*>(&wbar[c4]);
    float val = fmaxf(acc.x * dv, 0.f) * wv.x + fmaxf(acc.y * dv, 0.f) * wv.y +
                fmaxf(acc.z * dv, 0.f) * wv.z + fmaxf(acc.w * dv, 0.f) * wv.w;
    int t = threadIdx.x;
    s[t] = val; __syncthreads();
    for (int d = 64; d > 0; d >>= 1) {
        if ((t & 127) < d) s[t] += s[t + d];
        __syncthreads();
    }
    if ((t & 127) == 0) g[i] = s[t] * dv * a[i];
}

// ---------------- final reductions ----------------
__global__ __launch_bounds__(1024) void k_yred(const float* __restrict__ g,
                                               float* __restrict__ ys, int slot) {
    __shared__ float s[1024];
    int t = threadIdx.x;
    s[t] = g[t] + g[t + 1024] + g[t + 2048] + g[t + 3072];
    __syncthreads();
    for (int d = 512; d > 0; d >>= 1) { if (t < d) s[t] += s[t + d]; __syncthreads(); }
    if (t == 0) ys[slot] = s[0];
}

__global__ void k_fin(const float* __restrict__ ys, float* __restrict__ out) {
    float y0 = ys[0] / (float)NN, y1 = ys[1] / (float)NN;
    out[0] = 1.0f / (1.0f + expf(-(y0 - y1)));
    out[1] = y0;
    out[2] = y1;
}

// ---------------- launch ----------------
extern "C" void kernel_launch(void* const* d_in, const int* in_sizes, int n_in,
                              void* d_out, int out_size, void* d_ws, size_t ws_size,
                              hipStream_t stream) {
    const float* fts[2] = { (const float*)d_in[0], (const float*)d_in[1] };
    const float* W1 = (const float*)d_in[2];
    const float* W2 = (const float*)d_in[3];
    float* out = (float*)d_out;

    char* p = (char*)d_ws;
    auto alloc = [&](size_t b) { char* r = p; p += (b + 255) & ~(size_t)255; return r; };
    float* G    = (float*)alloc((size_t)NN * NN * 4);        // 64 MB; reused as chunk-partial buffer
    float* nrm  = (float*)alloc((size_t)NN * 4);
    float* qs   = (float*)alloc((size_t)NN * 4);
    int*   idx  = (int*)  alloc((size_t)NN * 16 * 4);
    int*   Dv   = (int*)  alloc((size_t)NN * 4);
    float* dvv  = (float*)alloc((size_t)NN * 4);
    float* rs1  = (float*)alloc((size_t)NN * 4);
    int*   offs = (int*)  alloc((size_t)(NN + 1) * 4);
    int*   cur  = (int*)  alloc((size_t)NN * 4);
    int*   coffs= (int*)  alloc((size_t)(NN + 1) * 4);
    int*   nch  = (int*)  alloc(4);
    int*   tnode= (int*)  alloc((size_t)MAXCH * 4);
    int*   adj  = (int*)  alloc((size_t)NN * KTOT * 4);
    signed char* Xqh = (signed char*)alloc((size_t)NN * CC);
    signed char* Xql = (signed char*)alloc((size_t)NN * CC);
    signed char* Wqh = (signed char*)alloc((size_t)HIDN * CC);
    signed char* Wql = (signed char*)alloc((size_t)HIDN * CC);
    unsigned* sigb   = (unsigned*)alloc((size_t)HIDN * 4);
    float* w1sig = (float*)alloc((size_t)HIDN * 4);
    ushort_t* t1b = (ushort_t*)alloc((size_t)NN * HIDN * 2);
    ushort_t* m   = (ushort_t*)alloc((size_t)NE * HIDN * 2);
    float* wbar = (float*)alloc((size_t)HIDN * 4);
    float* a    = (float*)alloc((size_t)NN * 4);
    float* g    = (float*)alloc((size_t)NN * 4);
    float* ys   = (float*)alloc(2 * 4);

    float* partial = G;   // chunk partials alias G (free after k_topk)

    hipMemsetAsync(sigb, 0, HIDN * 4, stream);
    k_w1max<<<CC / 64, 256, 0, stream>>>(W1, sigb);
    k_sig<<<HIDN / 256, 256, 0, stream>>>(sigb, w1sig);
    k_wt8<<<dim3(HIDN / 32, CC / 32), 256, 0, stream>>>(W1, w1sig, Wqh, Wql);
    k_w2bar<<<HIDN / 256, 256, 0, stream>>>(W2, wbar);

    for (int s = 0; s < 2; ++s) {
        const float* X = fts[s];
        k_rowprep<<<NN, 256, 0, stream>>>(X, nrm, qs, Xqh, Xql);
        k_mm8<true, false><<<528, 256, 0, stream>>>(Xqh, Xql, Xqh, Xql, qs, qs, G, nullptr, NN);
        k_topk<<<NN, 256, 0, stream>>>(G, nrm, idx);
        hipMemsetAsync(Dv, 0, NN * 4, stream);
        k_count<<<NN * KTOT / 256, 256, 0, stream>>>(idx, Dv);
        k_scan<<<1, 1024, 0, stream>>>(Dv, qs, dvv, rs1, offs, cur, coffs, nch, tnode);
        k_fill<<<NN * KTOT / 256, 256, 0, stream>>>(idx, cur, adj);
        hipMemsetAsync(a, 0, NN * 4, stream);
        k_zescat<<<NE / 256, 256, 0, stream>>>(idx, dvv, a);
        // conv1: t1b = bf16(dv * (X @ W1)) via i8 split; edge means; chunked gather
        k_mm8<false, true><<<dim3(HIDN / 128, NN / 128), 256, 0, stream>>>(Xqh, Xql, Wqh, Wql, rs1, w1sig, nullptr, t1b, HIDN);
        k_edge3<<<NN * 64 / 256, 256, 0, stream>>>(idx, t1b, m);
        k_chunk<<<(MAXCH + 3) / 4, 256, 0, stream>>>(offs, coffs, tnode, nch, adj, m, partial);
        // layer-2 collapsed: g[i] = a_i * (relu(u1_i) . wbar); y = sum(g)/N
        k_comb2<<<NN * 128 / 256, 256, 0, stream>>>(coffs, dvv, a, wbar, partial, g);
        k_yred<<<1, 1024, 0, stream>>>(g, ys, s);
    }
    k_fin<<<1, 1, 0, stream>>>(ys, out);
}